// Round 1
// baseline (60.032 us; speedup 1.0000x reference)
//
#include <hip/hip_runtime.h>
#include <hip/hip_bf16.h>

#define N_CELLS  16384
#define N_SPOTS  4096
#define N_LABELS 512
#define CPB      16   // cells per block (main kernel)
#define CT       4    // cell tile (simultaneous cells in inner loop)

// ---------------------------------------------------------------------------
// Kernel A: deterministic counting sort of spots by label.
// 1 block, 512 threads (one thread per label).
// Outputs to workspace: sorted_xy[N_SPOTS] (float2), start[N_LABELS+1], cnt[N_LABELS]
// ---------------------------------------------------------------------------
__global__ __launch_bounds__(512) void build_sorted_kernel(
    const float* __restrict__ ex, const float* __restrict__ ey,
    const int* __restrict__ labels,
    float2* __restrict__ sorted_xy, int* __restrict__ start_out,
    int* __restrict__ cnt_out)
{
    __shared__ int            s_lab[N_SPOTS];     // 16 KB
    __shared__ unsigned short s_idx[N_SPOTS];     // 8 KB
    __shared__ int            s_cnt[N_LABELS];
    __shared__ int            s_scan[N_LABELS];
    __shared__ int            s_cur[N_LABELS];

    const int t = threadIdx.x;  // 0..511 == label id

    s_cnt[t] = 0;
    for (int i = t; i < N_SPOTS; i += 512) s_lab[i] = labels[i];
    __syncthreads();

    // histogram
    for (int i = t; i < N_SPOTS; i += 512) atomicAdd(&s_cnt[s_lab[i]], 1);
    __syncthreads();

    // inclusive Hillis-Steele scan over 512 counts
    s_scan[t] = s_cnt[t];
    __syncthreads();
    for (int off = 1; off < N_LABELS; off <<= 1) {
        int add = (t >= off) ? s_scan[t - off] : 0;
        __syncthreads();
        s_scan[t] += add;
        __syncthreads();
    }

    const int my_cnt   = s_cnt[t];
    const int my_start = s_scan[t] - my_cnt;  // exclusive prefix
    s_cur[t] = my_start;
    __syncthreads();

    // scatter spot indices (order within a label is nondeterministic here...)
    for (int i = t; i < N_SPOTS; i += 512) {
        int p = atomicAdd(&s_cur[s_lab[i]], 1);
        s_idx[p] = (unsigned short)i;
    }
    __syncthreads();

    // ...so insertion-sort each segment by spot index -> fully deterministic
    for (int a = my_start + 1; a < my_start + my_cnt; ++a) {
        unsigned short key = s_idx[a];
        int b = a - 1;
        while (b >= my_start && s_idx[b] > key) { s_idx[b + 1] = s_idx[b]; --b; }
        s_idx[b + 1] = key;
    }

    // emit sorted coordinates + metadata
    for (int p = my_start; p < my_start + my_cnt; ++p) {
        int s = s_idx[p];
        sorted_xy[p] = make_float2(ex[s], ey[s]);
    }
    start_out[t] = my_start;
    cnt_out[t]   = my_cnt;
    if (t == 0) start_out[N_LABELS] = N_SPOTS;
}

// ---------------------------------------------------------------------------
// Kernel B: main. One thread per label, CPB cells per block, CT cells at a
// time in the inner loop. Spot table staged once per block in LDS.
// out[cell*512 + label] = norm * sum_{s in label} exp(-d2/(2D)) + cnt*1e-12
// ---------------------------------------------------------------------------
__global__ __launch_bounds__(512) void diffusion_main_kernel(
    const float* __restrict__ z, const float* __restrict__ dconst,
    const float2* __restrict__ sorted_xy, const int* __restrict__ start,
    const int* __restrict__ cnt, float* __restrict__ out)
{
    __shared__ float2 s_xy[N_SPOTS];  // 32 KB

    const int t = threadIdx.x;  // label id

    // stage sorted spot table, coalesced float4 loads
    {
        const float4* src = (const float4*)sorted_xy;
        float4*       dst = (float4*)s_xy;
        #pragma unroll
        for (int i = 0; i < N_SPOTS / 2 / 512; ++i)
            dst[t + i * 512] = src[t + i * 512];
    }

    const int   my_start = start[t];
    const int   my_cnt   = cnt[t];
    const float D    = dconst[0];
    const float c1   = -1.4426950408889634f / (2.0f * D);  // -log2(e)/(2D)
    const float norm = 1.0f / (6.28318530717958647f * D);  // 1/(2*pi*D)
    const float base = (float)my_cnt * 1e-12f;             // hoisted UNDERFLOW_NU

    __syncthreads();

    const int cell0 = blockIdx.x * CPB;
    for (int cc = 0; cc < CPB; cc += CT) {
        float zx[CT], zy[CT], acc[CT];
        #pragma unroll
        for (int k = 0; k < CT; ++k) {
            int cell = cell0 + cc + k;
            zx[k] = z[2 * cell];
            zy[k] = z[2 * cell + 1];
            acc[k] = 0.0f;
        }
        const int e = my_start + my_cnt;
        for (int p = my_start; p < e; ++p) {
            float2 xy = s_xy[p];
            #pragma unroll
            for (int k = 0; k < CT; ++k) {
                float dx = xy.x - zx[k];
                float dy = xy.y - zy[k];
                float d2 = fmaf(dx, dx, dy * dy);
                acc[k] += exp2f(d2 * c1);
            }
        }
        #pragma unroll
        for (int k = 0; k < CT; ++k) {
            int cell = cell0 + cc + k;
            out[(size_t)cell * N_LABELS + t] = fmaf(acc[k], norm, base);
        }
    }
}

// ---------------------------------------------------------------------------
extern "C" void kernel_launch(void* const* d_in, const int* in_sizes, int n_in,
                              void* d_out, int out_size, void* d_ws, size_t ws_size,
                              hipStream_t stream)
{
    const float* z      = (const float*)d_in[0];  // (16384, 2)
    const float* dconst = (const float*)d_in[1];  // scalar
    const float* ex     = (const float*)d_in[2];  // (4096,)
    const float* ey     = (const float*)d_in[3];  // (4096,)
    const int*   labels = (const int*)d_in[4];    // (4096,)
    float*       out    = (float*)d_out;          // (16384, 512)

    // workspace layout
    float2* sorted_xy = (float2*)d_ws;                              // 32 KB
    int*    start     = (int*)((char*)d_ws + N_SPOTS * sizeof(float2)); // 513 ints
    int*    cnt       = start + (N_LABELS + 1);                     // 512 ints

    build_sorted_kernel<<<1, 512, 0, stream>>>(ex, ey, labels, sorted_xy, start, cnt);

    diffusion_main_kernel<<<N_CELLS / CPB, 512, 0, stream>>>(
        z, dconst, sorted_xy, start, cnt, out);
}

// Round 2
// 45.173 us; speedup vs baseline: 1.3289x; 1.3289x over previous
//
#include <hip/hip_runtime.h>
#include <hip/hip_bf16.h>

#define N_CELLS  16384
#define N_SPOTS  4096
#define N_LABELS 512
#define NTHREADS 512
#define CPB      16      // cells per block (all processed in one pass)
#define TABLE    6144    // padded spot-table capacity (float2); expected ~5200 used
#define MAXSEG   32      // register-sort capacity per label segment

// ---------------------------------------------------------------------------
// Setup (1 block, 512 threads):
//  - histogram labels, rank labels by count desc (tie: label asc)
//  - thread/rank r handles label rlab[r]; wave segments padded to wave max
//  - scatter spot indices into padded segments, register-bitonic-sort each
//    segment (stable by spot index), emit pre-scaled coords + pads
//  meta layout (ints): [0,512): seg start  [512,1024): trip (wave-uniform)
//                      [1024,1536): label  [1536,2048): real count
// ---------------------------------------------------------------------------
__global__ __launch_bounds__(512) void build_kernel(
    const float* __restrict__ ex, const float* __restrict__ ey,
    const int* __restrict__ labels, const float* __restrict__ dconst,
    float2* __restrict__ table, int* __restrict__ meta)
{
    __shared__ unsigned short s_lab[N_SPOTS];   // 8 KB
    __shared__ int s_c[N_LABELS];               // per-label count
    __shared__ int s_h2[128];                   // histogram of counts
    __shared__ int s_rlab[N_LABELS];            // rank -> label
    __shared__ int s_rcnt[N_LABELS];            // rank -> count
    __shared__ int s_wmax[8];                   // per-wave max count
    __shared__ int s_cur[N_LABELS];             // scatter cursors (by label)
    __shared__ unsigned short s_idx[TABLE];     // 12 KB padded index table

    const int t = threadIdx.x;
    const int lane = t & 63, w = t >> 6;

    s_c[t] = 0;
    if (t < 128) s_h2[t] = 0;
    for (int i = t; i < N_SPOTS; i += NTHREADS) s_lab[i] = (unsigned short)labels[i];
    __syncthreads();

    for (int i = t; i < N_SPOTS; i += NTHREADS) atomicAdd(&s_c[s_lab[i]], 1);
    __syncthreads();

    const int myc = s_c[t];
    atomicAdd(&s_h2[myc < 127 ? myc : 127], 1);
    __syncthreads();

    // rank = #labels with larger count + #earlier labels with equal count
    int r = 0;
    for (int k = myc + 1; k < 128; ++k) r += s_h2[k];
    for (int j = 0; j < t; ++j) r += (s_c[j] == myc) ? 1 : 0;
    s_rlab[r] = t;
    s_rcnt[r] = myc;
    __syncthreads();

    // per-wave max over rank space (thread t ~ rank t)
    int v = s_rcnt[t];
    #pragma unroll
    for (int off = 32; off; off >>= 1) { int o = __shfl_xor(v, off); v = v > o ? v : o; }
    if (lane == 0) s_wmax[w] = v;
    __syncthreads();

    int pb = 0;
    #pragma unroll
    for (int w2 = 0; w2 < 8; ++w2) if (w2 < w) pb += s_wmax[w2];
    const int mytrip  = s_wmax[w];
    const int my_start = 64 * pb + lane * mytrip;

    for (int i = t; i < TABLE; i += NTHREADS) s_idx[i] = 0xFFFFu;  // sentinels
    s_cur[s_rlab[t]] = my_start;
    __syncthreads();

    for (int i = t; i < N_SPOTS; i += NTHREADS) {
        int l = s_lab[i];
        int p = atomicAdd(&s_cur[l], 1);
        if (p < TABLE) s_idx[p] = (unsigned short)i;
    }
    __syncthreads();

    const float Dv = dconst[0];
    const float sc = sqrtf(0.5f / Dv);   // prescale so dx'^2+dy'^2 = d2/(2D)

    if (mytrip <= MAXSEG) {
        // register bitonic sort, fully static indexing
        unsigned key[MAXSEG];
        #pragma unroll
        for (int k = 0; k < MAXSEG; ++k)
            key[k] = (k < mytrip && my_start + k < TABLE)
                         ? (unsigned)s_idx[my_start + k] : 0xFFFFu;
        #pragma unroll
        for (int kk = 2; kk <= MAXSEG; kk <<= 1) {
            #pragma unroll
            for (int j = kk >> 1; j > 0; j >>= 1) {
                #pragma unroll
                for (int i = 0; i < MAXSEG; ++i) {
                    int ixj = i ^ j;
                    if (ixj > i) {
                        unsigned a = key[i], b = key[ixj];
                        unsigned lo = a < b ? a : b, hi = a < b ? b : a;
                        if ((i & kk) == 0) { key[i] = lo; key[ixj] = hi; }
                        else               { key[i] = hi; key[ixj] = lo; }
                    }
                }
            }
        }
        #pragma unroll
        for (int k = 0; k < MAXSEG; ++k) {
            if (k < mytrip && my_start + k < TABLE) {
                unsigned s = key[k];
                float2 val = (s == 0xFFFFu) ? make_float2(1e9f, 0.f)
                                            : make_float2(ex[s] * sc, ey[s] * sc);
                table[my_start + k] = val;
            }
        }
    } else {
        // rare fallback: LDS insertion sort (wave-uniform branch)
        for (int a = my_start + 1; a < my_start + mytrip && a < TABLE; ++a) {
            unsigned short kv = s_idx[a];
            int b = a - 1;
            while (b >= my_start && s_idx[b] > kv) { s_idx[b + 1] = s_idx[b]; --b; }
            s_idx[b + 1] = kv;
        }
        for (int k = 0; k < mytrip && my_start + k < TABLE; ++k) {
            unsigned s = s_idx[my_start + k];
            float2 val = (s == 0xFFFFu) ? make_float2(1e9f, 0.f)
                                        : make_float2(ex[s] * sc, ey[s] * sc);
            table[my_start + k] = val;
        }
    }

    meta[t]                = my_start;
    meta[NTHREADS + t]     = mytrip;
    meta[2 * NTHREADS + t] = s_rlab[t];
    meta[3 * NTHREADS + t] = s_rcnt[t];
}

// ---------------------------------------------------------------------------
// Main: thread t owns one label (rank t), uniform scalar trip count per wave,
// 16 cells per block in one pass (16 exps per LDS read), transpose epilogue
// for coalesced output stores.
// ---------------------------------------------------------------------------
__global__ __launch_bounds__(512, 6) void diffusion_main_kernel(
    const float* __restrict__ z, const float* __restrict__ dconst,
    const float2* __restrict__ table, const int* __restrict__ meta,
    float* __restrict__ out)
{
    __shared__ float smem[TABLE * 2];   // 48 KB: spot table, then reused as transpose buf
    float2* s_xy = (float2*)smem;

    const int t = threadIdx.x;

    // stage padded table (coalesced float4)
    {
        const float4* src = (const float4*)table;
        float4* dst = (float4*)smem;
        #pragma unroll
        for (int i = 0; i < TABLE * 2 / 4 / NTHREADS; ++i)   // 6 iters
            dst[t + i * NTHREADS] = src[t + i * NTHREADS];
    }

    const int my_start = meta[t];
    const int trip     = __builtin_amdgcn_readfirstlane(meta[NTHREADS + t]); // wave-uniform
    const int my_lab   = meta[2 * NTHREADS + t];
    const float cntf   = (float)meta[3 * NTHREADS + t];

    const float D    = dconst[0];
    const float sc   = sqrtf(0.5f / D);
    const float norm = 1.0f / (6.28318530717958647f * D);
    const float base = cntf * 1e-12f;   // hoisted UNDERFLOW_NU

    const int cell0 = blockIdx.x * CPB;
    float zx[CPB], zy[CPB], acc[CPB];
    #pragma unroll
    for (int k = 0; k < CPB; ++k) {
        zx[k] = z[2 * (cell0 + k)]     * sc;   // uniform -> scalar loads
        zy[k] = z[2 * (cell0 + k) + 1] * sc;
        acc[k] = 0.0f;
    }
    __syncthreads();

    const float2* seg = s_xy + my_start;
    for (int p = 0; p < trip; ++p) {           // scalar loop control
        float2 xy = seg[p];
        #pragma unroll
        for (int k = 0; k < CPB; ++k) {
            float dx = xy.x - zx[k];
            float dy = xy.y - zy[k];
            float nd2 = fmaf(-dx, dx, -(dy * dy));   // -(d2/(2D))
            acc[k] += __expf(nd2);                    // v_mul + v_exp_f32
        }
    }
    __syncthreads();

    // transpose in LDS so global stores are coalesced
    float* tr = smem;   // [CPB][512]
    #pragma unroll
    for (int k = 0; k < CPB; ++k)
        tr[k * N_LABELS + my_lab] = fmaf(acc[k], norm, base);
    __syncthreads();

    const float4* tr4 = (const float4*)smem;
    float4* out4 = (float4*)(out + (size_t)cell0 * N_LABELS);
    #pragma unroll
    for (int rr = 0; rr < CPB * N_LABELS / 4 / NTHREADS; ++rr)   // 4 iters
        out4[t + rr * NTHREADS] = tr4[t + rr * NTHREADS];
}

// ---------------------------------------------------------------------------
extern "C" void kernel_launch(void* const* d_in, const int* in_sizes, int n_in,
                              void* d_out, int out_size, void* d_ws, size_t ws_size,
                              hipStream_t stream)
{
    const float* z      = (const float*)d_in[0];  // (16384, 2)
    const float* dconst = (const float*)d_in[1];  // scalar
    const float* ex     = (const float*)d_in[2];  // (4096,)
    const float* ey     = (const float*)d_in[3];  // (4096,)
    const int*   labels = (const int*)d_in[4];    // (4096,)
    float*       out    = (float*)d_out;          // (16384, 512)

    float2* table = (float2*)d_ws;                                  // 48 KB
    int*    meta  = (int*)((char*)d_ws + (size_t)TABLE * sizeof(float2)); // 8 KB

    build_kernel<<<1, NTHREADS, 0, stream>>>(ex, ey, labels, dconst, table, meta);

    diffusion_main_kernel<<<N_CELLS / CPB, NTHREADS, 0, stream>>>(
        z, dconst, table, meta, out);
}

// Round 3
// 38.982 us; speedup vs baseline: 1.5400x; 1.1588x over previous
//
#include <hip/hip_runtime.h>
#include <hip/hip_bf16.h>

#define N_CELLS  16384
#define N_SPOTS  4096
#define N_LABELS 512
#define NTHREADS 512
#define CPB      8       // cells per block (main kernel)
#define TABLE    6144    // padded spot-table capacity (float2)
#define MAXSEG   32      // register-sort capacity per label segment

#if defined(__has_builtin)
#if __has_builtin(__builtin_amdgcn_exp2f)
#define FAST_EXP2(x) __builtin_amdgcn_exp2f(x)
#else
#define FAST_EXP2(x) exp2f(x)
#endif
#else
#define FAST_EXP2(x) exp2f(x)
#endif

// log2(e)/2 : fold both 1/(2D) and log2(e) into the coordinate prescale
#define HALF_LOG2E 0.72134752044448170f

// ---------------------------------------------------------------------------
// Setup (1 block, 512 threads):
//  - histogram labels; rank labels by (count desc, label asc) — ballot-based
//  - wave segments padded to wave max; spot indices scattered, register-
//    bitonic-sorted per segment (deterministic), coords pre-scaled by
//    sqrt(log2e/(2D)) and emitted INTERLEAVED per wave:
//        table[wbase + p*64 + lane]  (one coalesced 512B line per trip)
//  meta (ints): [0,512): wave base  [512,1024): trip  [1024,1536): label
//               [1536,2048): real count
// ---------------------------------------------------------------------------
__global__ __launch_bounds__(512) void build_kernel(
    const float* __restrict__ ex, const float* __restrict__ ey,
    const int* __restrict__ labels, const float* __restrict__ dconst,
    float2* __restrict__ table, int* __restrict__ meta)
{
    __shared__ unsigned short s_lab[N_SPOTS];   // 8 KB
    __shared__ int s_c[N_LABELS];
    __shared__ int s_h2[128];
    __shared__ int s_suf[128];                  // suffix sums of h2
    __shared__ int s_pcw[32 * 8];               // per-(count,wave) label counts
    __shared__ int s_rlab[N_LABELS];
    __shared__ int s_rcnt[N_LABELS];
    __shared__ int s_wmax[8];
    __shared__ int s_wbase[8];
    __shared__ int s_cur[N_LABELS];
    __shared__ unsigned short s_idx[TABLE];     // 12 KB

    const int t = threadIdx.x;
    const int lane = t & 63, w = t >> 6;

    s_c[t] = 0;
    if (t < 128) s_h2[t] = 0;
    for (int i = t; i < N_SPOTS; i += NTHREADS) s_lab[i] = (unsigned short)labels[i];
    __syncthreads();

    for (int i = t; i < N_SPOTS; i += NTHREADS) atomicAdd(&s_c[s_lab[i]], 1);
    __syncthreads();

    const int myc  = s_c[t];
    const int mycc = myc < 127 ? myc : 127;
    atomicAdd(&s_h2[mycc], 1);
    __syncthreads();

    // suffix-scan h2: s_suf[v] = #labels with count >= v
    if (t < 128) s_suf[t] = s_h2[t];
    __syncthreads();
    for (int off = 1; off < 128; off <<= 1) {
        int add = (t < 128 && t + off < 128) ? s_suf[t + off] : 0;
        __syncthreads();
        if (t < 128) s_suf[t] += add;
        __syncthreads();
    }

    // position among equal-count labels (by label id asc), ballot-based
    int pos_w = 0;
    for (int v = 0; v < 32; ++v) {
        unsigned long long mask = __ballot(myc == v);
        if (myc == v) pos_w = __popcll(mask & ((1ull << lane) - 1ull));
        if (lane == 0) s_pcw[v * 8 + w] = __popcll(mask);
    }
    __syncthreads();
    int pos;
    if (myc < 32) {
        pos = pos_w;
        for (int w2 = 0; w2 < w; ++w2) pos += s_pcw[myc * 8 + w2];
    } else {  // astronomically rare for Poisson(8); deterministic fallback
        pos = 0;
        for (int j = 0; j < t; ++j) pos += (s_c[j] == myc) ? 1 : 0;
    }
    const int r = ((myc < 127) ? s_suf[myc + 1] : 0) + pos;   // rank
    s_rlab[r] = t;
    s_rcnt[r] = myc;
    __syncthreads();

    // per-wave max count over rank space
    int v = s_rcnt[t];
    #pragma unroll
    for (int off = 32; off; off >>= 1) { int o = __shfl_xor(v, off); v = v > o ? v : o; }
    if (lane == 0) s_wmax[w] = v;
    __syncthreads();
    if (t == 0) {
        int pb = 0;
        #pragma unroll
        for (int w2 = 0; w2 < 8; ++w2) { s_wbase[w2] = 64 * pb; pb += s_wmax[w2]; }
    }
    __syncthreads();

    const int mytrip    = s_wmax[w];
    const int wbase     = s_wbase[w];
    const int lin_start = wbase + lane * mytrip;   // contiguous scatter space

    for (int i = t; i < TABLE; i += NTHREADS) s_idx[i] = 0xFFFFu;  // sentinels
    s_cur[s_rlab[t]] = lin_start;
    __syncthreads();

    for (int i = t; i < N_SPOTS; i += NTHREADS) {
        int l = s_lab[i];
        int p = atomicAdd(&s_cur[l], 1);
        if (p < TABLE) s_idx[p] = (unsigned short)i;
    }
    __syncthreads();

    const float Dv = dconst[0];
    const float sc = sqrtf(HALF_LOG2E / Dv);  // so dx'^2+dy'^2 = d2*log2e/(2D)

    if (mytrip <= MAXSEG) {
        // register bitonic sort, fully static indexing (stable by spot index)
        unsigned key[MAXSEG];
        #pragma unroll
        for (int k = 0; k < MAXSEG; ++k)
            key[k] = (k < mytrip && lin_start + k < TABLE)
                         ? (unsigned)s_idx[lin_start + k] : 0xFFFFu;
        #pragma unroll
        for (int kk = 2; kk <= MAXSEG; kk <<= 1) {
            #pragma unroll
            for (int j = kk >> 1; j > 0; j >>= 1) {
                #pragma unroll
                for (int i = 0; i < MAXSEG; ++i) {
                    int ixj = i ^ j;
                    if (ixj > i) {
                        unsigned a = key[i], b = key[ixj];
                        unsigned lo = a < b ? a : b, hi = a < b ? b : a;
                        if ((i & kk) == 0) { key[i] = lo; key[ixj] = hi; }
                        else               { key[i] = hi; key[ixj] = lo; }
                    }
                }
            }
        }
        #pragma unroll
        for (int k = 0; k < MAXSEG; ++k) {
            if (k < mytrip) {
                int idx = wbase + k * 64 + lane;        // interleaved layout
                if (idx < TABLE) {
                    unsigned s = key[k];
                    float2 val = (s == 0xFFFFu) ? make_float2(1e8f, 0.f)
                                                : make_float2(ex[s] * sc, ey[s] * sc);
                    table[idx] = val;
                }
            }
        }
    } else {
        // rare fallback: LDS insertion sort (wave-uniform branch)
        for (int a = lin_start + 1; a < lin_start + mytrip && a < TABLE; ++a) {
            unsigned short kv = s_idx[a];
            int b = a - 1;
            while (b >= lin_start && s_idx[b] > kv) { s_idx[b + 1] = s_idx[b]; --b; }
            s_idx[b + 1] = kv;
        }
        for (int k = 0; k < mytrip; ++k) {
            int idx = wbase + k * 64 + lane;
            if (idx < TABLE && lin_start + k < TABLE) {
                unsigned s = s_idx[lin_start + k];
                float2 val = (s == 0xFFFFu) ? make_float2(1e8f, 0.f)
                                            : make_float2(ex[s] * sc, ey[s] * sc);
                table[idx] = val;
            }
        }
    }

    meta[t]                = wbase;
    meta[NTHREADS + t]     = mytrip;
    meta[2 * NTHREADS + t] = s_rlab[t];
    meta[3 * NTHREADS + t] = s_rcnt[t];
}

// ---------------------------------------------------------------------------
// Main: thread t owns one label (rank t); trip is wave-uniform scalar; spot
// table read straight from L2 (interleaved layout -> one coalesced 512B load
// per trip, depth-1 software prefetch). 8 cells per block; LDS only for the
// output transpose.
// ---------------------------------------------------------------------------
__global__ __launch_bounds__(512) void diffusion_main_kernel(
    const float* __restrict__ z, const float* __restrict__ dconst,
    const float2* __restrict__ table, const int* __restrict__ meta,
    float* __restrict__ out)
{
    __shared__ float tr[CPB * N_LABELS];   // 16 KB transpose buffer

    const int t = threadIdx.x;
    const int lane = t & 63;

    const int wbase  = __builtin_amdgcn_readfirstlane(meta[t]);
    const int trip   = __builtin_amdgcn_readfirstlane(meta[NTHREADS + t]);
    const int my_lab = meta[2 * NTHREADS + t];
    const float cntf = (float)meta[3 * NTHREADS + t];

    const float D    = dconst[0];
    const float sc   = sqrtf(HALF_LOG2E / D);
    const float norm = 1.0f / (6.28318530717958647f * D);
    const float base = cntf * 1e-12f;      // hoisted UNDERFLOW_NU

    const int cell0 = blockIdx.x * CPB;
    float zx[CPB], zy[CPB], acc[CPB];
    #pragma unroll
    for (int k = 0; k < CPB; ++k) {
        zx[k] = z[2 * (cell0 + k)]     * sc;   // wave-uniform -> scalar loads
        zy[k] = z[2 * (cell0 + k) + 1] * sc;
        acc[k] = 0.0f;
    }

    const float2* seg = table + wbase + lane;
    if (trip > 0) {
        float2 xy = seg[0];
        for (int p = 0; p < trip; ++p) {
            int pn = (p + 1 < trip) ? p + 1 : p;       // scalar select
            float2 nxt = seg[(size_t)pn * 64];          // prefetch next line
            #pragma unroll
            for (int k = 0; k < CPB; ++k) {
                float dx = xy.x - zx[k];
                float dy = xy.y - zy[k];
                float nd2 = fmaf(-dx, dx, -(dy * dy)); // -(d2*log2e/(2D))
                acc[k] += FAST_EXP2(nd2);              // v_exp_f32
            }
            xy = nxt;
        }
    }

    // transpose in LDS so global stores are coalesced
    #pragma unroll
    for (int k = 0; k < CPB; ++k)
        tr[k * N_LABELS + my_lab] = fmaf(acc[k], norm, base);
    __syncthreads();

    const float4* tr4 = (const float4*)tr;
    float4* out4 = (float4*)(out + (size_t)cell0 * N_LABELS);
    #pragma unroll
    for (int rr = 0; rr < CPB * N_LABELS / 4 / NTHREADS; ++rr)   // 2 iters
        out4[t + rr * NTHREADS] = tr4[t + rr * NTHREADS];
}

// ---------------------------------------------------------------------------
extern "C" void kernel_launch(void* const* d_in, const int* in_sizes, int n_in,
                              void* d_out, int out_size, void* d_ws, size_t ws_size,
                              hipStream_t stream)
{
    const float* z      = (const float*)d_in[0];  // (16384, 2)
    const float* dconst = (const float*)d_in[1];  // scalar
    const float* ex     = (const float*)d_in[2];  // (4096,)
    const float* ey     = (const float*)d_in[3];  // (4096,)
    const int*   labels = (const int*)d_in[4];    // (4096,)
    float*       out    = (float*)d_out;          // (16384, 512)

    float2* table = (float2*)d_ws;                                        // 48 KB
    int*    meta  = (int*)((char*)d_ws + (size_t)TABLE * sizeof(float2)); // 8 KB

    build_kernel<<<1, NTHREADS, 0, stream>>>(ex, ey, labels, dconst, table, meta);

    diffusion_main_kernel<<<N_CELLS / CPB, NTHREADS, 0, stream>>>(
        z, dconst, table, meta, out);
}

// Round 4
// 38.656 us; speedup vs baseline: 1.5530x; 1.0084x over previous
//
#include <hip/hip_runtime.h>
#include <hip/hip_bf16.h>

#define N_CELLS  16384
#define N_SPOTS  4096
#define N_LABELS 512
#define NTHREADS 512
#define CPB      8       // cells per block (main kernel)
#define NPAIR    (CPB/2) // packed-f32 cell pairs
#define TABLE    6144    // padded spot-table capacity (float2)
#define MAXSEG   32      // register-sort capacity per label segment

typedef float v2f __attribute__((ext_vector_type(2)));

#if defined(__has_builtin)
#if __has_builtin(__builtin_amdgcn_exp2f)
#define FAST_EXP2(x) __builtin_amdgcn_exp2f(x)
#else
#define FAST_EXP2(x) exp2f(x)
#endif
#else
#define FAST_EXP2(x) exp2f(x)
#endif

// log2(e)/2 : fold both 1/(2D) and log2(e) into the coordinate prescale
#define HALF_LOG2E 0.72134752044448170f

// ---------------------------------------------------------------------------
// Setup (1 block, 512 threads) — unchanged from round 3 (works, ~3-4 us):
// rank labels by (count desc, label asc); wave segments padded to wave max;
// register-bitonic sort per segment; coords pre-scaled by sqrt(log2e/(2D)),
// emitted interleaved per wave: table[wbase + p*64 + lane].
// meta (ints): [0,512): wave base  [512,1024): trip  [1024,1536): label
//              [1536,2048): real count
// ---------------------------------------------------------------------------
__global__ __launch_bounds__(512) void build_kernel(
    const float* __restrict__ ex, const float* __restrict__ ey,
    const int* __restrict__ labels, const float* __restrict__ dconst,
    float2* __restrict__ table, int* __restrict__ meta)
{
    __shared__ unsigned short s_lab[N_SPOTS];   // 8 KB
    __shared__ int s_c[N_LABELS];
    __shared__ int s_h2[128];
    __shared__ int s_suf[128];                  // suffix sums of h2
    __shared__ int s_pcw[32 * 8];               // per-(count,wave) label counts
    __shared__ int s_rlab[N_LABELS];
    __shared__ int s_rcnt[N_LABELS];
    __shared__ int s_wmax[8];
    __shared__ int s_wbase[8];
    __shared__ int s_cur[N_LABELS];
    __shared__ unsigned short s_idx[TABLE];     // 12 KB

    const int t = threadIdx.x;
    const int lane = t & 63, w = t >> 6;

    s_c[t] = 0;
    if (t < 128) s_h2[t] = 0;
    for (int i = t; i < N_SPOTS; i += NTHREADS) s_lab[i] = (unsigned short)labels[i];
    __syncthreads();

    for (int i = t; i < N_SPOTS; i += NTHREADS) atomicAdd(&s_c[s_lab[i]], 1);
    __syncthreads();

    const int myc  = s_c[t];
    const int mycc = myc < 127 ? myc : 127;
    atomicAdd(&s_h2[mycc], 1);
    __syncthreads();

    if (t < 128) s_suf[t] = s_h2[t];
    __syncthreads();
    for (int off = 1; off < 128; off <<= 1) {
        int add = (t < 128 && t + off < 128) ? s_suf[t + off] : 0;
        __syncthreads();
        if (t < 128) s_suf[t] += add;
        __syncthreads();
    }

    int pos_w = 0;
    for (int v = 0; v < 32; ++v) {
        unsigned long long mask = __ballot(myc == v);
        if (myc == v) pos_w = __popcll(mask & ((1ull << lane) - 1ull));
        if (lane == 0) s_pcw[v * 8 + w] = __popcll(mask);
    }
    __syncthreads();
    int pos;
    if (myc < 32) {
        pos = pos_w;
        for (int w2 = 0; w2 < w; ++w2) pos += s_pcw[myc * 8 + w2];
    } else {
        pos = 0;
        for (int j = 0; j < t; ++j) pos += (s_c[j] == myc) ? 1 : 0;
    }
    const int r = ((myc < 127) ? s_suf[myc + 1] : 0) + pos;
    s_rlab[r] = t;
    s_rcnt[r] = myc;
    __syncthreads();

    int v = s_rcnt[t];
    #pragma unroll
    for (int off = 32; off; off >>= 1) { int o = __shfl_xor(v, off); v = v > o ? v : o; }
    if (lane == 0) s_wmax[w] = v;
    __syncthreads();
    if (t == 0) {
        int pb = 0;
        #pragma unroll
        for (int w2 = 0; w2 < 8; ++w2) { s_wbase[w2] = 64 * pb; pb += s_wmax[w2]; }
    }
    __syncthreads();

    const int mytrip    = s_wmax[w];
    const int wbase     = s_wbase[w];
    const int lin_start = wbase + lane * mytrip;

    for (int i = t; i < TABLE; i += NTHREADS) s_idx[i] = 0xFFFFu;
    s_cur[s_rlab[t]] = lin_start;
    __syncthreads();

    for (int i = t; i < N_SPOTS; i += NTHREADS) {
        int l = s_lab[i];
        int p = atomicAdd(&s_cur[l], 1);
        if (p < TABLE) s_idx[p] = (unsigned short)i;
    }
    __syncthreads();

    const float Dv = dconst[0];
    const float sc = sqrtf(HALF_LOG2E / Dv);

    if (mytrip <= MAXSEG) {
        unsigned key[MAXSEG];
        #pragma unroll
        for (int k = 0; k < MAXSEG; ++k)
            key[k] = (k < mytrip && lin_start + k < TABLE)
                         ? (unsigned)s_idx[lin_start + k] : 0xFFFFu;
        #pragma unroll
        for (int kk = 2; kk <= MAXSEG; kk <<= 1) {
            #pragma unroll
            for (int j = kk >> 1; j > 0; j >>= 1) {
                #pragma unroll
                for (int i = 0; i < MAXSEG; ++i) {
                    int ixj = i ^ j;
                    if (ixj > i) {
                        unsigned a = key[i], b = key[ixj];
                        unsigned lo = a < b ? a : b, hi = a < b ? b : a;
                        if ((i & kk) == 0) { key[i] = lo; key[ixj] = hi; }
                        else               { key[i] = hi; key[ixj] = lo; }
                    }
                }
            }
        }
        #pragma unroll
        for (int k = 0; k < MAXSEG; ++k) {
            if (k < mytrip) {
                int idx = wbase + k * 64 + lane;
                if (idx < TABLE) {
                    unsigned s = key[k];
                    float2 val = (s == 0xFFFFu) ? make_float2(1e8f, 0.f)
                                                : make_float2(ex[s] * sc, ey[s] * sc);
                    table[idx] = val;
                }
            }
        }
    } else {
        for (int a = lin_start + 1; a < lin_start + mytrip && a < TABLE; ++a) {
            unsigned short kv = s_idx[a];
            int b = a - 1;
            while (b >= lin_start && s_idx[b] > kv) { s_idx[b + 1] = s_idx[b]; --b; }
            s_idx[b + 1] = kv;
        }
        for (int k = 0; k < mytrip; ++k) {
            int idx = wbase + k * 64 + lane;
            if (idx < TABLE && lin_start + k < TABLE) {
                unsigned s = s_idx[lin_start + k];
                float2 val = (s == 0xFFFFu) ? make_float2(1e8f, 0.f)
                                            : make_float2(ex[s] * sc, ey[s] * sc);
                table[idx] = val;
            }
        }
    }

    meta[t]                = wbase;
    meta[NTHREADS + t]     = mytrip;
    meta[2 * NTHREADS + t] = s_rlab[t];
    meta[3 * NTHREADS + t] = s_rcnt[t];
}

// ---------------------------------------------------------------------------
// Main. Changes vs round 3:
//  - chunk rotation: wave w of block b handles rank-chunk (w+b)&7, so the
//    heavy chunk cycles across SIMDs among resident blocks (fixes the static
//    SIMD0 hotspot from count-ranked assignment)
//  - packed-f32 inner loop: cells paired into <2 x float>, lowering to
//    v_pk_add/v_pk_fma + 2x v_exp_f32 (halves VALU issue per pair)
// ---------------------------------------------------------------------------
__global__ __launch_bounds__(512) void diffusion_main_kernel(
    const float* __restrict__ z, const float* __restrict__ dconst,
    const v2f* __restrict__ table, const int* __restrict__ meta,
    float* __restrict__ out)
{
    __shared__ float tr[CPB * N_LABELS];   // 16 KB transpose buffer

    const int t = threadIdx.x;
    const int lane = t & 63, w = t >> 6;

    // rotated chunk assignment
    const int c = (w + (int)blockIdx.x) & 7;
    const int u = c * 64 + lane;

    const int wbase  = __builtin_amdgcn_readfirstlane(meta[u]);
    const int trip   = __builtin_amdgcn_readfirstlane(meta[NTHREADS + u]);
    const int my_lab = meta[2 * NTHREADS + u];
    const float cntf = (float)meta[3 * NTHREADS + u];

    const float D    = dconst[0];
    const float sc   = sqrtf(HALF_LOG2E / D);
    const float norm = 1.0f / (6.28318530717958647f * D);
    const float base = cntf * 1e-12f;      // hoisted UNDERFLOW_NU

    const int cell0 = blockIdx.x * CPB;
    v2f zxn[NPAIR], zyn[NPAIR], acc[NPAIR];
    #pragma unroll
    for (int j = 0; j < NPAIR; ++j) {
        // negated, prescaled cell coords, paired for pk ops
        zxn[j] = (v2f){ -z[2 * (cell0 + 2 * j)]     * sc,
                        -z[2 * (cell0 + 2 * j + 1)] * sc };
        zyn[j] = (v2f){ -z[2 * (cell0 + 2 * j) + 1]     * sc,
                        -z[2 * (cell0 + 2 * j + 1) + 1] * sc };
        acc[j] = (v2f){0.f, 0.f};
    }

    const v2f* seg = table + wbase + lane;
    if (trip > 0) {
        v2f xy = seg[0];
        for (int p = 0; p < trip; ++p) {
            int pn = (p + 1 < trip) ? p + 1 : p;    // scalar select
            v2f nxt = seg[(size_t)pn * 64];          // prefetch next line
            v2f xx = (v2f){xy.x, xy.x};
            v2f yy = (v2f){xy.y, xy.y};
            #pragma unroll
            for (int j = 0; j < NPAIR; ++j) {
                v2f dx = xx + zxn[j];                         // v_pk_add
                v2f dy = yy + zyn[j];                         // v_pk_add
                v2f m  = dy * dy;                             // v_pk_mul
                v2f nd2 = __builtin_elementwise_fma(-dx, dx, -m);  // v_pk_fma
                v2f e  = (v2f){ FAST_EXP2(nd2.x), FAST_EXP2(nd2.y) };
                acc[j] += e;                                  // v_pk_add
            }
            xy = nxt;
        }
    }

    // transpose in LDS so global stores are coalesced
    #pragma unroll
    for (int j = 0; j < NPAIR; ++j) {
        tr[(2 * j)     * N_LABELS + my_lab] = fmaf(acc[j].x, norm, base);
        tr[(2 * j + 1) * N_LABELS + my_lab] = fmaf(acc[j].y, norm, base);
    }
    __syncthreads();

    const float4* tr4 = (const float4*)tr;
    float4* out4 = (float4*)(out + (size_t)cell0 * N_LABELS);
    #pragma unroll
    for (int rr = 0; rr < CPB * N_LABELS / 4 / NTHREADS; ++rr)   // 2 iters
        out4[t + rr * NTHREADS] = tr4[t + rr * NTHREADS];
}

// ---------------------------------------------------------------------------
extern "C" void kernel_launch(void* const* d_in, const int* in_sizes, int n_in,
                              void* d_out, int out_size, void* d_ws, size_t ws_size,
                              hipStream_t stream)
{
    const float* z      = (const float*)d_in[0];  // (16384, 2)
    const float* dconst = (const float*)d_in[1];  // scalar
    const float* ex     = (const float*)d_in[2];  // (4096,)
    const float* ey     = (const float*)d_in[3];  // (4096,)
    const int*   labels = (const int*)d_in[4];    // (4096,)
    float*       out    = (float*)d_out;          // (16384, 512)

    float2* table = (float2*)d_ws;                                        // 48 KB
    int*    meta  = (int*)((char*)d_ws + (size_t)TABLE * sizeof(float2)); // 8 KB

    build_kernel<<<1, NTHREADS, 0, stream>>>(ex, ey, labels, dconst, table, meta);

    diffusion_main_kernel<<<N_CELLS / CPB, NTHREADS, 0, stream>>>(
        z, dconst, (const v2f*)table, meta, out);
}